// Round 26
// baseline (208.782 us; speedup 1.0000x reference)
//
#include <hip/hip_runtime.h>

#define N_NODES 100000
#define IN_DIM 64
#define EMB 128
#define N_EDGES 1600000
#define BN_EPS 1e-5f

// bucket partition
#define NB 98
#define BCAP 18432
#define FA_THREADS 512
#define FA_EPT 16
#define FA_BLK (FA_THREADS * FA_EPT)
#define FA_GRID ((N_EDGES + FA_BLK - 1) / FA_BLK)   // 196

// ---- workspace layout (bytes) ----
#define WS_GSUM     0
#define WS_GSUM2    512
#define WS_BCUR     1024
#define WS_ROWSTART 2048                    // ends 402052
#define WS_W1T      403456                  // 16384 B fp16 W1 transposed
#define WS_PAIRS    802304                  // 12.8 MB
#define WS_H16      13602304                // 25.6 MB region (h16 uses half)
#define WS_DSTARR   39202304                // 7.2 MB (dead after fillB2 -> x16 overlay)
#define WS_SWARR    46427648                // 14.5 MB (dead after fillB2)
#define WS_X16      WS_DSTARR
#define WS_ZERO_INTS 512

typedef _Float16 half8_t __attribute__((ext_vector_type(8)));
typedef _Float16 half4_t __attribute__((ext_vector_type(4)));
typedef _Float16 half2_t __attribute__((ext_vector_type(2)));
typedef float floatx4 __attribute__((ext_vector_type(4)));

// ---------------- zero + W1 -> fp16 transposed global sidecar ---------------
__global__ __launch_bounds__(512) void zero_cvtW1_kernel(
    int* __restrict__ p, const float* __restrict__ W1, _Float16* __restrict__ w1T)
{
    const int tid = threadIdx.x;
    p[tid] = 0;
    #pragma unroll
    for (int i = 0; i < 16; ++i) {
        int idx = i * 512 + tid;            // 0..8191
        int k = idx >> 7, c = idx & 127;
        w1T[c * 64 + k] = (_Float16)W1[idx];
    }
}

// ---------------- fillA: partition edges into 98 dst-buckets ----------------
__global__ __launch_bounds__(512) void fillA_kernel(
    const int* __restrict__ ei, const float* __restrict__ ew,
    int* __restrict__ bcur, int* __restrict__ dstArr, float2* __restrict__ swArr)
{
    __shared__ int cnt[NB], base[NB];
    const int tid = threadIdx.x;
    if (tid < NB) cnt[tid] = 0;
    __syncthreads();
    const int e0 = blockIdx.x * FA_BLK;
    int pk[FA_EPT];
    #pragma unroll
    for (int i = 0; i < FA_EPT; ++i) {
        int e = e0 + i * FA_THREADS + tid;
        pk[i] = -1;
        if (e < N_EDGES) {
            int d = ei[N_EDGES + e];
            int b = d >> 10;
            int pos = atomicAdd(&cnt[b], 1);   // LDS atomic
            pk[i] = (b << 13) | pos;
        }
    }
    __syncthreads();
    if (tid < NB) base[tid] = atomicAdd(&bcur[tid], cnt[tid]);
    __syncthreads();
    #pragma unroll
    for (int i = 0; i < FA_EPT; ++i) {
        int e = e0 + i * FA_THREADS + tid;
        if (pk[i] >= 0) {
            int b = pk[i] >> 13, pos = pk[i] & 8191;
            int idx = b * BCAP + base[b] + pos;
            dstArr[idx] = ei[N_EDGES + e];
            swArr[idx]  = make_float2(__int_as_float(ei[e]), ew[e]);
        }
    }
}

// ---------------- fillB2: hist + scan + rowstart + scatter ------------------
__global__ __launch_bounds__(1024) void fillB2_kernel(
    const int* __restrict__ bcur, const int* __restrict__ dstArr,
    const float2* __restrict__ swArr,
    int* __restrict__ rowstart, float2* __restrict__ pairs)
{
    __shared__ int cnt2[1024];
    __shared__ int pre[1024];
    __shared__ int sbk[128];
    const int g = blockIdx.x;
    const int tid = threadIdx.x;

    if (tid < 128) sbk[tid] = (tid < NB) ? bcur[tid] : 0;
    cnt2[tid] = 0;
    __syncthreads();
    for (int off = 1; off < 128; off <<= 1) {
        int v = 0;
        if (tid < 128 && tid >= off) v = sbk[tid - off];
        __syncthreads();
        if (tid < 128) sbk[tid] += v;
        __syncthreads();
    }
    const int bucketBase = (g > 0) ? sbk[g - 1] : 0;

    const int nE = bcur[g];
    const int segBase = g * BCAP;
    for (int j = tid; j < nE; j += 1024)
        atomicAdd(&cnt2[dstArr[segBase + j] & 1023], 1);
    __syncthreads();

    const int c = cnt2[tid];
    pre[tid] = c;
    __syncthreads();
    for (int off = 1; off < 1024; off <<= 1) {
        int v = (tid >= off) ? pre[tid - off] : 0;
        __syncthreads();
        pre[tid] += v;
        __syncthreads();
    }
    const int start = bucketBase + pre[tid] - c;
    const int node = g * 1024 + tid;
    if (node < N_NODES) rowstart[node] = start;
    if (node == N_NODES - 1) rowstart[N_NODES] = start + c;

    __syncthreads();
    cnt2[tid] = start;
    __syncthreads();
    #pragma unroll 4
    for (int j = tid; j < nE; j += 1024) {
        int d = dstArr[segBase + j];
        int p = atomicAdd(&cnt2[d & 1023], 1);
        pairs[p] = swArr[segBase + j];
    }
}

// ---------------- cvt: x -> fp16 sidecar ------------------------------------
__global__ __launch_bounds__(256) void cvt_kernel(
    const float4* __restrict__ x4, ushort4* __restrict__ x16)
{
    int i = blockIdx.x * 256 + threadIdx.x;
    if (i >= N_NODES * IN_DIM / 4) return;
    float4 v = x4[i];
    ushort4 u;
    _Float16 a = (_Float16)v.x, b = (_Float16)v.y,
             c = (_Float16)v.z, d = (_Float16)v.w;
    u.x = *(unsigned short*)&a; u.y = *(unsigned short*)&b;
    u.z = *(unsigned short*)&c; u.w = *(unsigned short*)&d;
    x16[i] = u;
}

// ---------------- fused gather + W1 GEMM + BN partials (v2) -----------------
// r25 post-mortem: per-block W1->LDS staging cost 27 KB LDS (occ 40%) + 2.9M
// bank conflicts. v2 loads B-frags from a global fp16 w1T (L2-hot 16 KB):
// LDS 8.7 KB -> occupancy cap back at 8 blocks/CU; no transpose scatter.
#define GG_NPW 8   // nodes per wave -> 32/block -> 3125 blocks
__global__ __launch_bounds__(256) void gath_gemv_kernel(
    const _Float16* __restrict__ x16,
    const int* __restrict__ rowstart,
    const float2* __restrict__ pairs,
    const _Float16* __restrict__ w1T,   // [128][64] fp16 (c-major)
    const float* __restrict__ b1,
    _Float16* __restrict__ h16,     // [N,128] fp16
    float* __restrict__ gsum, float* __restrict__ gsum2)
{
    __shared__ _Float16 Ah[32][72];       // A-tile: 32 node-rows fp16 (4.6 KB)
    __shared__ float redS[4][EMB], redQ[4][EMB];   // 4 KB

    const int tid  = threadIdx.x;
    const int lane = tid & 63;
    const int wid  = tid >> 6;
    const int e    = lane >> 4;     // edge slot 0..3
    const int f    = lane & 15;     // quad 0..15
    const int l15  = lane & 15;
    const int kb   = lane >> 4;
    const half4_t* __restrict__ xv4 = (const half4_t*)x16;
    const int node0 = blockIdx.x * 32;

    // zero BN partial arrays (read after barrier)
    #pragma unroll
    for (int i = 0; i < 2; ++i) {
        ((float*)redS)[i * 256 + tid] = 0.f;
        ((float*)redQ)[i * 256 + tid] = 0.f;
    }

    // ---- gather phase: each wave computes 8 node-rows into Ah ----
    for (int r = 0; r < GG_NPW; ++r) {
        const int n  = node0 + wid * GG_NPW + r;
        const int jb = rowstart[n];
        const int je = rowstart[n + 1];
        float4 accA = make_float4(0.f, 0.f, 0.f, 0.f);
        float4 accB = make_float4(0.f, 0.f, 0.f, 0.f);
        for (int j0 = jb; j0 < je; j0 += 64) {
            const int cnt = min(64, je - j0);
            float2 p = (lane < cnt) ? pairs[j0 + lane] : make_float2(0.f, 0.f);
            int   psrc = __float_as_int(p.x);
            float pw   = p.y;
            const int nch = (cnt + 7) >> 3;
            #pragma unroll 4
            for (int c = 0; c < nch; ++c) {
                int   uA = __shfl(psrc, c * 8 + e);
                float wA = __shfl(pw,   c * 8 + e);
                int   uB = __shfl(psrc, c * 8 + 4 + e);
                float wB = __shfl(pw,   c * 8 + 4 + e);
                half4_t va = xv4[(size_t)(unsigned)uA * 16 + f];
                half4_t vb = xv4[(size_t)(unsigned)uB * 16 + f];
                accA.x += wA * (float)va[0]; accA.y += wA * (float)va[1];
                accA.z += wA * (float)va[2]; accA.w += wA * (float)va[3];
                accB.x += wB * (float)vb[0]; accB.y += wB * (float)vb[1];
                accB.z += wB * (float)vb[2]; accB.w += wB * (float)vb[3];
            }
        }
        float4 s = make_float4(accA.x + accB.x, accA.y + accB.y,
                               accA.z + accB.z, accA.w + accB.w);
        s.x += __shfl_xor(s.x, 16); s.y += __shfl_xor(s.y, 16);
        s.z += __shfl_xor(s.z, 16); s.w += __shfl_xor(s.w, 16);
        s.x += __shfl_xor(s.x, 32); s.y += __shfl_xor(s.y, 32);
        s.z += __shfl_xor(s.z, 32); s.w += __shfl_xor(s.w, 32);
        if (e == 0) {   // lanes 0-15: add self term, store row as fp16
            half4_t sv = xv4[(size_t)n * 16 + f];
            half4_t hrow;
            hrow[0] = (_Float16)(s.x + (float)sv[0]);
            hrow[1] = (_Float16)(s.y + (float)sv[1]);
            hrow[2] = (_Float16)(s.z + (float)sv[2]);
            hrow[3] = (_Float16)(s.w + (float)sv[3]);
            *(half4_t*)&Ah[wid * GG_NPW + r][f * 4] = hrow;
        }
    }
    __syncthreads();   // Ah + red-zero complete

    // ---- MFMA phase: wave (rg,ch) does 16 rows x 64 cols ----
    const int rg  = wid >> 1;
    const int ch  = wid & 1;
    const int c0w = ch * 64;

    half8_t Bf[4][2];
    #pragma unroll
    for (int ct = 0; ct < 4; ++ct)
        #pragma unroll
        for (int kc = 0; kc < 2; ++kc)
            Bf[ct][kc] = *(const half8_t*)&w1T[(c0w + ct * 16 + l15) * 64 + kc * 32 + kb * 8];
    float b1c[4];
    #pragma unroll
    for (int ct = 0; ct < 4; ++ct) b1c[ct] = b1[c0w + ct * 16 + l15];

    half8_t af[2];
    #pragma unroll
    for (int kc = 0; kc < 2; ++kc)
        af[kc] = *(half8_t*)&Ah[rg * 16 + l15][kc * 32 + kb * 8];

    floatx4 acc[4];
    #pragma unroll
    for (int ct = 0; ct < 4; ++ct)
        acc[ct] = (floatx4){b1c[ct], b1c[ct], b1c[ct], b1c[ct]};
    #pragma unroll
    for (int kc = 0; kc < 2; ++kc)
        #pragma unroll
        for (int ct = 0; ct < 4; ++ct)
            acc[ct] = __builtin_amdgcn_mfma_f32_16x16x32_f16(af[kc], Bf[ct][kc], acc[ct], 0, 0, 0);

    float sA[4] = {0, 0, 0, 0}, qA[4] = {0, 0, 0, 0};
    #pragma unroll
    for (int ct = 0; ct < 4; ++ct) {
        #pragma unroll
        for (int i = 0; i < 4; ++i) {
            const int r = node0 + rg * 16 + kb * 4 + i;
            const float v = acc[ct][i];
            h16[(size_t)r * EMB + c0w + ct * 16 + l15] = (_Float16)v;
            sA[ct] += v;
            qA[ct] += v * v;
        }
    }
    #pragma unroll
    for (int ct = 0; ct < 4; ++ct) {
        sA[ct] += __shfl_xor(sA[ct], 16); sA[ct] += __shfl_xor(sA[ct], 32);
        qA[ct] += __shfl_xor(qA[ct], 16); qA[ct] += __shfl_xor(qA[ct], 32);
    }
    if (lane < 16) {
        #pragma unroll
        for (int ct = 0; ct < 4; ++ct) {
            redS[wid][c0w + ct * 16 + lane] = sA[ct];
            redQ[wid][c0w + ct * 16 + lane] = qA[ct];
        }
    }
    __syncthreads();
    if (tid < EMB) {
        float s = redS[0][tid] + redS[1][tid] + redS[2][tid] + redS[3][tid];
        float q = redQ[0][tid] + redQ[1][tid] + redQ[2][tid] + redQ[3][tid];
        atomicAdd(&gsum[tid],  s);
        atomicAdd(&gsum2[tid], q);
    }
}

// ---------------- mlp2: out = relu(BN(h16)) @ W2 + b2 (fp16 in, fp32 out) ---
#define MR 32
#define M2_ITERS 5
#define M2_ROWS (MR * M2_ITERS)   // 160 rows/block -> 625 blocks

__global__ __launch_bounds__(256) void mlp2_kernel(
    const _Float16* __restrict__ h16,
    float* __restrict__ out,
    const float* __restrict__ gsum, const float* __restrict__ gsum2,
    const float* __restrict__ gamma, const float* __restrict__ beta,
    const float* __restrict__ W2,   // [128,128] row-major, fp32
    const float* __restrict__ b2)
{
    __shared__ _Float16 Ph[MR][136];
    __shared__ float abuf[EMB], bbuf[EMB];

    const int tid  = threadIdx.x;
    const int lane = tid & 63;
    const int wid  = tid >> 6;
    const int rg   = wid >> 1;
    const int ch   = wid & 1;
    const int c0w  = ch * 64;
    const int l15  = lane & 15;
    const int kb   = lane >> 4;

    if (tid < EMB) {
        const float invN = 1.0f / (float)N_NODES;
        float mean = gsum[tid] * invN;
        float var  = gsum2[tid] * invN - mean * mean;
        float inv  = rsqrtf(var + BN_EPS);
        float a    = gamma[tid] * inv;
        abuf[tid] = a;
        bbuf[tid] = beta[tid] - mean * a;
    }

    const int bcol = c0w + l15;
    half8_t Bf[4][4];
    #pragma unroll
    for (int ct = 0; ct < 4; ++ct) {
        #pragma unroll
        for (int kc = 0; kc < 4; ++kc) {
            #pragma unroll
            for (int i = 0; i < 8; ++i)
                Bf[ct][kc][i] = (_Float16)W2[(kc * 32 + kb * 8 + i) * EMB + ct * 16 + bcol];
        }
    }
    float b2c[4];
    #pragma unroll
    for (int ct = 0; ct < 4; ++ct) b2c[ct] = b2[ct * 16 + bcol];

    __syncthreads();

    const int r0blk = blockIdx.x * M2_ROWS;
    for (int it = 0; it < M2_ITERS; ++it) {
        const int r0 = r0blk + it * MR;
        #pragma unroll
        for (int i = 0; i < 8; ++i) {
            int j   = i * 256 + tid;
            int row = j >> 6;
            int c2  = (j & 63) * 2;
            half2_t hv = *(const half2_t*)&h16[(size_t)(r0 + row) * EMB + c2];
            float p0 = fmaxf((float)hv[0] * abuf[c2]     + bbuf[c2],     0.f);
            float p1 = fmaxf((float)hv[1] * abuf[c2 + 1] + bbuf[c2 + 1], 0.f);
            Ph[row][c2]     = (_Float16)p0;
            Ph[row][c2 + 1] = (_Float16)p1;
        }
        __syncthreads();

        floatx4 acc[4];
        #pragma unroll
        for (int ct = 0; ct < 4; ++ct)
            acc[ct] = (floatx4){b2c[ct], b2c[ct], b2c[ct], b2c[ct]};
        #pragma unroll
        for (int kc = 0; kc < 4; ++kc) {
            half8_t af = *(half8_t*)&Ph[rg * 16 + l15][kc * 32 + kb * 8];
            #pragma unroll
            for (int ct = 0; ct < 4; ++ct)
                acc[ct] = __builtin_amdgcn_mfma_f32_16x16x32_f16(af, Bf[ct][kc], acc[ct], 0, 0, 0);
        }
        __syncthreads();

        #pragma unroll
        for (int ct = 0; ct < 4; ++ct) {
            #pragma unroll
            for (int i = 0; i < 4; ++i) {
                int row = r0 + rg * 16 + kb * 4 + i;
                out[(size_t)row * EMB + c0w + ct * 16 + l15] = acc[ct][i];
            }
        }
    }
}

extern "C" void kernel_launch(void* const* d_in, const int* in_sizes, int n_in,
                              void* d_out, int out_size, void* d_ws, size_t ws_size,
                              hipStream_t stream)
{
    const float* x     = (const float*)d_in[0];
    const int*   ei    = (const int*)d_in[1];   // int32 [2,E]
    const float* ew    = (const float*)d_in[3];
    const float* W1    = (const float*)d_in[4];
    const float* b1    = (const float*)d_in[5];
    const float* gamma = (const float*)d_in[6];
    const float* beta  = (const float*)d_in[7];
    const float* W2    = (const float*)d_in[8];
    const float* b2    = (const float*)d_in[9];

    char* ws = (char*)d_ws;
    float*    gsum     = (float*)(ws + WS_GSUM);
    float*    gsum2    = (float*)(ws + WS_GSUM2);
    int*      bcur     = (int*)(ws + WS_BCUR);
    int*      rowstart = (int*)(ws + WS_ROWSTART);
    _Float16* w1T      = (_Float16*)(ws + WS_W1T);
    float2*   pairs    = (float2*)(ws + WS_PAIRS);
    _Float16* h16      = (_Float16*)(ws + WS_H16);
    int*      dstArr   = (int*)(ws + WS_DSTARR);
    float2*   swArr    = (float2*)(ws + WS_SWARR);
    _Float16* x16      = (_Float16*)(ws + WS_X16);
    float*    out      = (float*)d_out;

    zero_cvtW1_kernel<<<1, WS_ZERO_INTS, 0, stream>>>((int*)d_ws, W1, w1T);
    fillA_kernel<<<FA_GRID, FA_THREADS, 0, stream>>>(ei, ew, bcur, dstArr, swArr);
    fillB2_kernel<<<NB, 1024, 0, stream>>>(bcur, dstArr, swArr, rowstart, pairs);
    cvt_kernel<<<(N_NODES * IN_DIM / 4 + 255) / 256, 256, 0, stream>>>(
        (const float4*)x, (ushort4*)x16);
    gath_gemv_kernel<<<N_NODES / 32, 256, 0, stream>>>(
        x16, rowstart, pairs, w1T, b1, h16, gsum, gsum2);
    mlp2_kernel<<<N_NODES / M2_ROWS, 256, 0, stream>>>(h16, out, gsum, gsum2, gamma, beta, W2, b2);
}

// Round 27
// 176.612 us; speedup vs baseline: 1.1822x; 1.1822x over previous
//
#include <hip/hip_runtime.h>

#define N_NODES 100000
#define IN_DIM 64
#define EMB 128
#define N_EDGES 1600000
#define BN_EPS 1e-5f

// bucket partition
#define NB 98
#define BCAP 18432
#define FA_THREADS 512
#define FA_EPT 16
#define FA_BLK (FA_THREADS * FA_EPT)
#define FA_GRID ((N_EDGES + FA_BLK - 1) / FA_BLK)   // 196

// ---- workspace layout (bytes) ----
#define WS_GSUM     0
#define WS_GSUM2    512
#define WS_BCUR     1024
#define WS_ROWSTART 2048                    // ends 402052
#define WS_W1T      403456                  // 16 KB fp16 W1 transposed
#define WS_PAIRS    802304                  // 12.8 MB (h16 overlays AFTER gather)
#define WS_H16      WS_PAIRS
#define WS_AGG      13602304                // 25.6 MB fp32
#define WS_DSTARR   39202304                // 7.2 MB (dead after fillB2 -> x16 overlay)
#define WS_SWARR    46427648                // 14.5 MB (dead after fillB2)
#define WS_X16      WS_DSTARR
#define WS_ZERO_INTS 512

typedef _Float16 half8_t __attribute__((ext_vector_type(8)));
typedef _Float16 half4_t __attribute__((ext_vector_type(4)));
typedef _Float16 half2_t __attribute__((ext_vector_type(2)));
typedef float floatx4 __attribute__((ext_vector_type(4)));

// ---------------- zero + W1 -> fp16 transposed global sidecar ---------------
__global__ __launch_bounds__(512) void zero_cvtW1_kernel(
    int* __restrict__ p, const float* __restrict__ W1, _Float16* __restrict__ w1T)
{
    const int tid = threadIdx.x;
    p[tid] = 0;
    #pragma unroll
    for (int i = 0; i < 16; ++i) {
        int idx = i * 512 + tid;            // 0..8191
        int k = idx >> 7, c = idx & 127;
        w1T[c * 64 + k] = (_Float16)W1[idx];
    }
}

// ---------------- fillA: partition edges into 98 dst-buckets ----------------
__global__ __launch_bounds__(512) void fillA_kernel(
    const int* __restrict__ ei, const float* __restrict__ ew,
    int* __restrict__ bcur, int* __restrict__ dstArr, float2* __restrict__ swArr)
{
    __shared__ int cnt[NB], base[NB];
    const int tid = threadIdx.x;
    if (tid < NB) cnt[tid] = 0;
    __syncthreads();
    const int e0 = blockIdx.x * FA_BLK;
    int pk[FA_EPT];
    #pragma unroll
    for (int i = 0; i < FA_EPT; ++i) {
        int e = e0 + i * FA_THREADS + tid;
        pk[i] = -1;
        if (e < N_EDGES) {
            int d = ei[N_EDGES + e];
            int b = d >> 10;
            int pos = atomicAdd(&cnt[b], 1);   // LDS atomic
            pk[i] = (b << 13) | pos;
        }
    }
    __syncthreads();
    if (tid < NB) base[tid] = atomicAdd(&bcur[tid], cnt[tid]);
    __syncthreads();
    #pragma unroll
    for (int i = 0; i < FA_EPT; ++i) {
        int e = e0 + i * FA_THREADS + tid;
        if (pk[i] >= 0) {
            int b = pk[i] >> 13, pos = pk[i] & 8191;
            int idx = b * BCAP + base[b] + pos;
            dstArr[idx] = ei[N_EDGES + e];
            swArr[idx]  = make_float2(__int_as_float(ei[e]), ew[e]);
        }
    }
}

// ---------------- fillB2: hist + scan + rowstart + scatter ------------------
__global__ __launch_bounds__(1024) void fillB2_kernel(
    const int* __restrict__ bcur, const int* __restrict__ dstArr,
    const float2* __restrict__ swArr,
    int* __restrict__ rowstart, float2* __restrict__ pairs)
{
    __shared__ int cnt2[1024];
    __shared__ int pre[1024];
    __shared__ int sbk[128];
    const int g = blockIdx.x;
    const int tid = threadIdx.x;

    if (tid < 128) sbk[tid] = (tid < NB) ? bcur[tid] : 0;
    cnt2[tid] = 0;
    __syncthreads();
    for (int off = 1; off < 128; off <<= 1) {
        int v = 0;
        if (tid < 128 && tid >= off) v = sbk[tid - off];
        __syncthreads();
        if (tid < 128) sbk[tid] += v;
        __syncthreads();
    }
    const int bucketBase = (g > 0) ? sbk[g - 1] : 0;

    const int nE = bcur[g];
    const int segBase = g * BCAP;
    for (int j = tid; j < nE; j += 1024)
        atomicAdd(&cnt2[dstArr[segBase + j] & 1023], 1);
    __syncthreads();

    const int c = cnt2[tid];
    pre[tid] = c;
    __syncthreads();
    for (int off = 1; off < 1024; off <<= 1) {
        int v = (tid >= off) ? pre[tid - off] : 0;
        __syncthreads();
        pre[tid] += v;
        __syncthreads();
    }
    const int start = bucketBase + pre[tid] - c;
    const int node = g * 1024 + tid;
    if (node < N_NODES) rowstart[node] = start;
    if (node == N_NODES - 1) rowstart[N_NODES] = start + c;

    __syncthreads();
    cnt2[tid] = start;
    __syncthreads();
    #pragma unroll 4
    for (int j = tid; j < nE; j += 1024) {
        int d = dstArr[segBase + j];
        int p = atomicAdd(&cnt2[d & 1023], 1);
        pairs[p] = swArr[segBase + j];
    }
}

// ---------------- cvt: x -> fp16 sidecar ------------------------------------
__global__ __launch_bounds__(256) void cvt_kernel(
    const float4* __restrict__ x4, ushort4* __restrict__ x16)
{
    int i = blockIdx.x * 256 + threadIdx.x;
    if (i >= N_NODES * IN_DIM / 4) return;
    float4 v = x4[i];
    ushort4 u;
    _Float16 a = (_Float16)v.x, b = (_Float16)v.y,
             c = (_Float16)v.z, d = (_Float16)v.w;
    u.x = *(unsigned short*)&a; u.y = *(unsigned short*)&b;
    u.z = *(unsigned short*)&c; u.w = *(unsigned short*)&d;
    x16[i] = u;
}

// ---------------- gather v4: e/f lane map on fp16 rows ----------------------
#define G_NPW 5
__global__ __launch_bounds__(256) void gather_kernel(
    const _Float16* __restrict__ x16,
    const int* __restrict__ rowstart,
    const float2* __restrict__ pairs,
    float* __restrict__ agg)
{
    const int tid  = threadIdx.x;
    const int lane = tid & 63;
    const int wid  = tid >> 6;
    const int e    = lane >> 4;
    const int f    = lane & 15;
    const half4_t* __restrict__ xv4 = (const half4_t*)x16;
    const int node0 = (blockIdx.x * 4 + wid) * G_NPW;

    for (int r = 0; r < G_NPW; ++r) {
        const int n  = node0 + r;
        const int jb = rowstart[n];
        const int je = rowstart[n + 1];
        float4 accA = make_float4(0.f, 0.f, 0.f, 0.f);
        float4 accB = make_float4(0.f, 0.f, 0.f, 0.f);
        for (int j0 = jb; j0 < je; j0 += 64) {
            const int cnt = min(64, je - j0);
            float2 p = (lane < cnt) ? pairs[j0 + lane] : make_float2(0.f, 0.f);
            int   psrc = __float_as_int(p.x);
            float pw   = p.y;
            const int nch = (cnt + 7) >> 3;
            #pragma unroll 4
            for (int c = 0; c < nch; ++c) {
                int   uA = __shfl(psrc, c * 8 + e);
                float wA = __shfl(pw,   c * 8 + e);
                int   uB = __shfl(psrc, c * 8 + 4 + e);
                float wB = __shfl(pw,   c * 8 + 4 + e);
                half4_t va = xv4[(size_t)(unsigned)uA * 16 + f];
                half4_t vb = xv4[(size_t)(unsigned)uB * 16 + f];
                accA.x += wA * (float)va[0]; accA.y += wA * (float)va[1];
                accA.z += wA * (float)va[2]; accA.w += wA * (float)va[3];
                accB.x += wB * (float)vb[0]; accB.y += wB * (float)vb[1];
                accB.z += wB * (float)vb[2]; accB.w += wB * (float)vb[3];
            }
        }
        float4 s = make_float4(accA.x + accB.x, accA.y + accB.y,
                               accA.z + accB.z, accA.w + accB.w);
        s.x += __shfl_xor(s.x, 16); s.y += __shfl_xor(s.y, 16);
        s.z += __shfl_xor(s.z, 16); s.w += __shfl_xor(s.w, 16);
        s.x += __shfl_xor(s.x, 32); s.y += __shfl_xor(s.y, 32);
        s.z += __shfl_xor(s.z, 32); s.w += __shfl_xor(s.w, 32);
        if (e == 0)
            *(float4*)&agg[(size_t)n * IN_DIM + f * 4] = s;
    }
}

// ---------------- gemv v5: 1 tile/wave, B-frags from global fp16 w1T --------
// r24 post-mortem: 44us was the per-block 8192-elem W1 prologue (4 variants
// pinned). v5: no staging at all -- 16x16B B-frag loads from L2-hot 16 KB
// w1T, A direct from global, LDS only for BN reduction. 1563 blocks.
#define GV_TILES (N_NODES / 16)                 // 6250
#define GV_GRID ((GV_TILES + 3) / 4)            // 1563
__global__ __launch_bounds__(256) void gemv_kernel(
    const float* __restrict__ agg,
    const float* __restrict__ x,
    const _Float16* __restrict__ w1T,   // [128][64] fp16 (c-major)
    const float* __restrict__ b1,
    _Float16* __restrict__ h16,         // [N,128] fp16 (pairs region, no alias)
    float* __restrict__ gsum, float* __restrict__ gsum2)
{
    __shared__ float redS[4][EMB], redQ[4][EMB];

    const int tid  = threadIdx.x;
    const int lane = tid & 63;
    const int wid  = tid >> 6;
    const int l15  = lane & 15;
    const int kb   = lane >> 4;

    float sA[8] = {0,0,0,0,0,0,0,0};
    float qA[8] = {0,0,0,0,0,0,0,0};

    const int t = blockIdx.x * 4 + wid;
    if (t < GV_TILES) {
        half8_t Bf[8][2];
        #pragma unroll
        for (int ct = 0; ct < 8; ++ct)
            #pragma unroll
            for (int kc = 0; kc < 2; ++kc)
                Bf[ct][kc] = *(const half8_t*)&w1T[(ct * 16 + l15) * 64 + kc * 32 + kb * 8];
        float b1c[8];
        #pragma unroll
        for (int ct = 0; ct < 8; ++ct) b1c[ct] = b1[ct * 16 + l15];

        const size_t rowb = (size_t)(t * 16 + l15) * IN_DIM + kb * 8;
        half8_t af[2];
        #pragma unroll
        for (int kc = 0; kc < 2; ++kc) {
            float4 a0 = *(const float4*)(agg + rowb + kc * 32);
            float4 a1 = *(const float4*)(agg + rowb + kc * 32 + 4);
            float4 x0 = *(const float4*)(x   + rowb + kc * 32);
            float4 x1 = *(const float4*)(x   + rowb + kc * 32 + 4);
            af[kc][0] = (_Float16)(a0.x + x0.x);
            af[kc][1] = (_Float16)(a0.y + x0.y);
            af[kc][2] = (_Float16)(a0.z + x0.z);
            af[kc][3] = (_Float16)(a0.w + x0.w);
            af[kc][4] = (_Float16)(a1.x + x1.x);
            af[kc][5] = (_Float16)(a1.y + x1.y);
            af[kc][6] = (_Float16)(a1.z + x1.z);
            af[kc][7] = (_Float16)(a1.w + x1.w);
        }
        floatx4 acc[8];
        #pragma unroll
        for (int ct = 0; ct < 8; ++ct)
            acc[ct] = (floatx4){b1c[ct], b1c[ct], b1c[ct], b1c[ct]};
        #pragma unroll
        for (int kc = 0; kc < 2; ++kc)
            #pragma unroll
            for (int ct = 0; ct < 8; ++ct)
                acc[ct] = __builtin_amdgcn_mfma_f32_16x16x32_f16(af[kc], Bf[ct][kc], acc[ct], 0, 0, 0);
        #pragma unroll
        for (int ct = 0; ct < 8; ++ct) {
            #pragma unroll
            for (int i = 0; i < 4; ++i) {
                const int r = t * 16 + kb * 4 + i;
                const float v = acc[ct][i];
                h16[(size_t)r * EMB + ct * 16 + l15] = (_Float16)v;
                sA[ct] += v;
                qA[ct] += v * v;
            }
        }
    }

    // reduce duplicates across kb lanes, then cross-wave via LDS, then atomics
    #pragma unroll
    for (int ct = 0; ct < 8; ++ct) {
        sA[ct] += __shfl_xor(sA[ct], 16); sA[ct] += __shfl_xor(sA[ct], 32);
        qA[ct] += __shfl_xor(qA[ct], 16); qA[ct] += __shfl_xor(qA[ct], 32);
    }
    if (lane < 16) {
        #pragma unroll
        for (int ct = 0; ct < 8; ++ct) {
            redS[wid][ct * 16 + lane] = sA[ct];
            redQ[wid][ct * 16 + lane] = qA[ct];
        }
    }
    __syncthreads();
    if (tid < EMB) {
        float s = redS[0][tid] + redS[1][tid] + redS[2][tid] + redS[3][tid];
        float q = redQ[0][tid] + redQ[1][tid] + redQ[2][tid] + redQ[3][tid];
        atomicAdd(&gsum[tid],  s);
        atomicAdd(&gsum2[tid], q);
    }
}

// ---------------- mlp2: out = relu(BN(h16)) @ W2 + b2 (fp16 in, fp32 out) ---
#define MR 32
#define M2_ITERS 5
#define M2_ROWS (MR * M2_ITERS)   // 160 rows/block -> 625 blocks

__global__ __launch_bounds__(256) void mlp2_kernel(
    const _Float16* __restrict__ h16,
    float* __restrict__ out,
    const float* __restrict__ gsum, const float* __restrict__ gsum2,
    const float* __restrict__ gamma, const float* __restrict__ beta,
    const float* __restrict__ W2,   // [128,128] row-major, fp32
    const float* __restrict__ b2)
{
    __shared__ _Float16 Ph[MR][136];
    __shared__ float abuf[EMB], bbuf[EMB];

    const int tid  = threadIdx.x;
    const int lane = tid & 63;
    const int wid  = tid >> 6;
    const int rg   = wid >> 1;
    const int ch   = wid & 1;
    const int c0w  = ch * 64;
    const int l15  = lane & 15;
    const int kb   = lane >> 4;

    if (tid < EMB) {
        const float invN = 1.0f / (float)N_NODES;
        float mean = gsum[tid] * invN;
        float var  = gsum2[tid] * invN - mean * mean;
        float inv  = rsqrtf(var + BN_EPS);
        float a    = gamma[tid] * inv;
        abuf[tid] = a;
        bbuf[tid] = beta[tid] - mean * a;
    }

    const int bcol = c0w + l15;
    half8_t Bf[4][4];
    #pragma unroll
    for (int ct = 0; ct < 4; ++ct) {
        #pragma unroll
        for (int kc = 0; kc < 4; ++kc) {
            #pragma unroll
            for (int i = 0; i < 8; ++i)
                Bf[ct][kc][i] = (_Float16)W2[(kc * 32 + kb * 8 + i) * EMB + ct * 16 + bcol];
        }
    }
    float b2c[4];
    #pragma unroll
    for (int ct = 0; ct < 4; ++ct) b2c[ct] = b2[ct * 16 + bcol];

    __syncthreads();

    const int r0blk = blockIdx.x * M2_ROWS;
    for (int it = 0; it < M2_ITERS; ++it) {
        const int r0 = r0blk + it * MR;
        #pragma unroll
        for (int i = 0; i < 8; ++i) {
            int j   = i * 256 + tid;
            int row = j >> 6;
            int c2  = (j & 63) * 2;
            half2_t hv = *(const half2_t*)&h16[(size_t)(r0 + row) * EMB + c2];
            float p0 = fmaxf((float)hv[0] * abuf[c2]     + bbuf[c2],     0.f);
            float p1 = fmaxf((float)hv[1] * abuf[c2 + 1] + bbuf[c2 + 1], 0.f);
            Ph[row][c2]     = (_Float16)p0;
            Ph[row][c2 + 1] = (_Float16)p1;
        }
        __syncthreads();

        floatx4 acc[4];
        #pragma unroll
        for (int ct = 0; ct < 4; ++ct)
            acc[ct] = (floatx4){b2c[ct], b2c[ct], b2c[ct], b2c[ct]};
        #pragma unroll
        for (int kc = 0; kc < 4; ++kc) {
            half8_t af = *(half8_t*)&Ph[rg * 16 + l15][kc * 32 + kb * 8];
            #pragma unroll
            for (int ct = 0; ct < 4; ++ct)
                acc[ct] = __builtin_amdgcn_mfma_f32_16x16x32_f16(af, Bf[ct][kc], acc[ct], 0, 0, 0);
        }
        __syncthreads();

        #pragma unroll
        for (int ct = 0; ct < 4; ++ct) {
            #pragma unroll
            for (int i = 0; i < 4; ++i) {
                int row = r0 + rg * 16 + kb * 4 + i;
                out[(size_t)row * EMB + c0w + ct * 16 + l15] = acc[ct][i];
            }
        }
    }
}

extern "C" void kernel_launch(void* const* d_in, const int* in_sizes, int n_in,
                              void* d_out, int out_size, void* d_ws, size_t ws_size,
                              hipStream_t stream)
{
    const float* x     = (const float*)d_in[0];
    const int*   ei    = (const int*)d_in[1];   // int32 [2,E]
    const float* ew    = (const float*)d_in[3];
    const float* W1    = (const float*)d_in[4];
    const float* b1    = (const float*)d_in[5];
    const float* gamma = (const float*)d_in[6];
    const float* beta  = (const float*)d_in[7];
    const float* W2    = (const float*)d_in[8];
    const float* b2    = (const float*)d_in[9];

    char* ws = (char*)d_ws;
    float*    gsum     = (float*)(ws + WS_GSUM);
    float*    gsum2    = (float*)(ws + WS_GSUM2);
    int*      bcur     = (int*)(ws + WS_BCUR);
    int*      rowstart = (int*)(ws + WS_ROWSTART);
    _Float16* w1T      = (_Float16*)(ws + WS_W1T);
    float2*   pairs    = (float2*)(ws + WS_PAIRS);
    _Float16* h16      = (_Float16*)(ws + WS_H16);   // pairs region, dead after gather
    float*    agg      = (float*)(ws + WS_AGG);
    int*      dstArr   = (int*)(ws + WS_DSTARR);
    float2*   swArr    = (float2*)(ws + WS_SWARR);
    _Float16* x16      = (_Float16*)(ws + WS_X16);
    float*    out      = (float*)d_out;

    zero_cvtW1_kernel<<<1, WS_ZERO_INTS, 0, stream>>>((int*)d_ws, W1, w1T);
    fillA_kernel<<<FA_GRID, FA_THREADS, 0, stream>>>(ei, ew, bcur, dstArr, swArr);
    fillB2_kernel<<<NB, 1024, 0, stream>>>(bcur, dstArr, swArr, rowstart, pairs);
    cvt_kernel<<<(N_NODES * IN_DIM / 4 + 255) / 256, 256, 0, stream>>>(
        (const float4*)x, (ushort4*)x16);
    gather_kernel<<<N_NODES / (4 * G_NPW), 256, 0, stream>>>(x16, rowstart, pairs, agg);
    gemv_kernel<<<GV_GRID, 256, 0, stream>>>(agg, x, w1T, b1, h16, gsum, gsum2);
    mlp2_kernel<<<N_NODES / M2_ROWS, 256, 0, stream>>>(h16, out, gsum, gsum2, gamma, beta, W2, b2);
}

// Round 28
// 151.330 us; speedup vs baseline: 1.3796x; 1.1671x over previous
//
#include <hip/hip_runtime.h>

#define N_NODES 100000
#define IN_DIM 64
#define EMB 128
#define N_EDGES 1600000
#define BN_EPS 1e-5f

// bucket partition
#define NB 98
#define BCAP 18432
#define FA_THREADS 512
#define FA_EPT 16
#define FA_BLK (FA_THREADS * FA_EPT)
#define FA_GRID ((N_EDGES + FA_BLK - 1) / FA_BLK)   // 196

// gemv tiling (r24 v4)
#define GV_TPW 3
#define GV_TILES (N_NODES / 16)                       // 6250
#define GV_GRID ((GV_TILES + 4 * GV_TPW - 1) / (4 * GV_TPW))   // 521

// ---- workspace layout (bytes) ----
#define WS_GSUM     0
#define WS_GSUM2    512
#define WS_BCUR     1024
#define WS_ROWSTART 2048                    // ends 402052
#define WS_PAIRS    802304                  // 12.8 MB
#define WS_AGG      13602304                // 25.6 MB (h16 overlays after gemv reads)
#define WS_DSTARR   39202304                // 7.2 MB (dead after fillB2 -> x16 overlay)
#define WS_SWARR    46427648                // 14.5 MB (dead after fillB2)
#define WS_X16      WS_DSTARR               // 12.8 MB, ends 52002304
#define WS_PART     52002560                // 2*128*521*4 = 533,504 B (dead region)
#define WS_ZERO_INTS 512

typedef _Float16 half8_t __attribute__((ext_vector_type(8)));
typedef _Float16 half4_t __attribute__((ext_vector_type(4)));
typedef _Float16 half2_t __attribute__((ext_vector_type(2)));
typedef float floatx4 __attribute__((ext_vector_type(4)));

// ---------------- zero: replaces hipMemsetAsync -----------------------------
__global__ __launch_bounds__(512) void zero_kernel(int* __restrict__ p)
{
    p[threadIdx.x] = 0;
}

// ---------------- fillA: partition edges into 98 dst-buckets ----------------
__global__ __launch_bounds__(512) void fillA_kernel(
    const int* __restrict__ ei, const float* __restrict__ ew,
    int* __restrict__ bcur, int* __restrict__ dstArr, float2* __restrict__ swArr)
{
    __shared__ int cnt[NB], base[NB];
    const int tid = threadIdx.x;
    if (tid < NB) cnt[tid] = 0;
    __syncthreads();
    const int e0 = blockIdx.x * FA_BLK;
    int pk[FA_EPT];
    #pragma unroll
    for (int i = 0; i < FA_EPT; ++i) {
        int e = e0 + i * FA_THREADS + tid;
        pk[i] = -1;
        if (e < N_EDGES) {
            int d = ei[N_EDGES + e];
            int b = d >> 10;
            int pos = atomicAdd(&cnt[b], 1);   // LDS atomic
            pk[i] = (b << 13) | pos;
        }
    }
    __syncthreads();
    if (tid < NB) base[tid] = atomicAdd(&bcur[tid], cnt[tid]);
    __syncthreads();
    #pragma unroll
    for (int i = 0; i < FA_EPT; ++i) {
        int e = e0 + i * FA_THREADS + tid;
        if (pk[i] >= 0) {
            int b = pk[i] >> 13, pos = pk[i] & 8191;
            int idx = b * BCAP + base[b] + pos;
            dstArr[idx] = ei[N_EDGES + e];
            swArr[idx]  = make_float2(__int_as_float(ei[e]), ew[e]);
        }
    }
}

// ---------------- fillB2: hist + scan + rowstart + scatter ------------------
__global__ __launch_bounds__(1024) void fillB2_kernel(
    const int* __restrict__ bcur, const int* __restrict__ dstArr,
    const float2* __restrict__ swArr,
    int* __restrict__ rowstart, float2* __restrict__ pairs)
{
    __shared__ int cnt2[1024];
    __shared__ int pre[1024];
    __shared__ int sbk[128];
    const int g = blockIdx.x;
    const int tid = threadIdx.x;

    if (tid < 128) sbk[tid] = (tid < NB) ? bcur[tid] : 0;
    cnt2[tid] = 0;
    __syncthreads();
    for (int off = 1; off < 128; off <<= 1) {
        int v = 0;
        if (tid < 128 && tid >= off) v = sbk[tid - off];
        __syncthreads();
        if (tid < 128) sbk[tid] += v;
        __syncthreads();
    }
    const int bucketBase = (g > 0) ? sbk[g - 1] : 0;

    const int nE = bcur[g];
    const int segBase = g * BCAP;
    for (int j = tid; j < nE; j += 1024)
        atomicAdd(&cnt2[dstArr[segBase + j] & 1023], 1);
    __syncthreads();

    const int c = cnt2[tid];
    pre[tid] = c;
    __syncthreads();
    for (int off = 1; off < 1024; off <<= 1) {
        int v = (tid >= off) ? pre[tid - off] : 0;
        __syncthreads();
        pre[tid] += v;
        __syncthreads();
    }
    const int start = bucketBase + pre[tid] - c;
    const int node = g * 1024 + tid;
    if (node < N_NODES) rowstart[node] = start;
    if (node == N_NODES - 1) rowstart[N_NODES] = start + c;

    __syncthreads();
    cnt2[tid] = start;
    __syncthreads();
    #pragma unroll 4
    for (int j = tid; j < nE; j += 1024) {
        int d = dstArr[segBase + j];
        int p = atomicAdd(&cnt2[d & 1023], 1);
        pairs[p] = swArr[segBase + j];
    }
}

// ---------------- cvt: x -> fp16 sidecar ------------------------------------
__global__ __launch_bounds__(256) void cvt_kernel(
    const float4* __restrict__ x4, ushort4* __restrict__ x16)
{
    int i = blockIdx.x * 256 + threadIdx.x;
    if (i >= N_NODES * IN_DIM / 4) return;
    float4 v = x4[i];
    ushort4 u;
    _Float16 a = (_Float16)v.x, b = (_Float16)v.y,
             c = (_Float16)v.z, d = (_Float16)v.w;
    u.x = *(unsigned short*)&a; u.y = *(unsigned short*)&b;
    u.z = *(unsigned short*)&c; u.w = *(unsigned short*)&d;
    x16[i] = u;
}

// ---------------- gather v4: e/f lane map on fp16 rows ----------------------
#define G_NPW 5
__global__ __launch_bounds__(256) void gather_kernel(
    const _Float16* __restrict__ x16,
    const int* __restrict__ rowstart,
    const float2* __restrict__ pairs,
    float* __restrict__ agg)
{
    const int tid  = threadIdx.x;
    const int lane = tid & 63;
    const int wid  = tid >> 6;
    const int e    = lane >> 4;
    const int f    = lane & 15;
    const half4_t* __restrict__ xv4 = (const half4_t*)x16;
    const int node0 = (blockIdx.x * 4 + wid) * G_NPW;

    for (int r = 0; r < G_NPW; ++r) {
        const int n  = node0 + r;
        const int jb = rowstart[n];
        const int je = rowstart[n + 1];
        float4 accA = make_float4(0.f, 0.f, 0.f, 0.f);
        float4 accB = make_float4(0.f, 0.f, 0.f, 0.f);
        for (int j0 = jb; j0 < je; j0 += 64) {
            const int cnt = min(64, je - j0);
            float2 p = (lane < cnt) ? pairs[j0 + lane] : make_float2(0.f, 0.f);
            int   psrc = __float_as_int(p.x);
            float pw   = p.y;
            const int nch = (cnt + 7) >> 3;
            #pragma unroll 4
            for (int c = 0; c < nch; ++c) {
                int   uA = __shfl(psrc, c * 8 + e);
                float wA = __shfl(pw,   c * 8 + e);
                int   uB = __shfl(psrc, c * 8 + 4 + e);
                float wB = __shfl(pw,   c * 8 + 4 + e);
                half4_t va = xv4[(size_t)(unsigned)uA * 16 + f];
                half4_t vb = xv4[(size_t)(unsigned)uB * 16 + f];
                accA.x += wA * (float)va[0]; accA.y += wA * (float)va[1];
                accA.z += wA * (float)va[2]; accA.w += wA * (float)va[3];
                accB.x += wB * (float)vb[0]; accB.y += wB * (float)vb[1];
                accB.z += wB * (float)vb[2]; accB.w += wB * (float)vb[3];
            }
        }
        float4 s = make_float4(accA.x + accB.x, accA.y + accB.y,
                               accA.z + accB.z, accA.w + accB.w);
        s.x += __shfl_xor(s.x, 16); s.y += __shfl_xor(s.y, 16);
        s.z += __shfl_xor(s.z, 16); s.w += __shfl_xor(s.w, 16);
        s.x += __shfl_xor(s.x, 32); s.y += __shfl_xor(s.y, 32);
        s.z += __shfl_xor(s.z, 32); s.w += __shfl_xor(s.w, 32);
        if (e == 0)
            *(float4*)&agg[(size_t)n * IN_DIM + f * 4] = s;
    }
}

// ---------------- gemv v4b: r24 exact + contention-free BN partials ---------
// Five gemv variants pinned 42-53us; only common factor = 256 global fp32
// atomics/block to the same 1 KB (serialized at L2). v4b writes per-block
// partials pS/pQ[col][block] (no atomics); bnred reduces them.
__global__ __launch_bounds__(256) void gemv_kernel(
    const float* __restrict__ agg,
    const float* __restrict__ x,
    const float* __restrict__ W1,   // [64,128] row-major, fp32
    const float* __restrict__ b1,
    _Float16* __restrict__ h16,     // [N,128] fp16 (overlays agg)
    float* __restrict__ pS, float* __restrict__ pQ)   // [128][GV_GRID]
{
    __shared__ _Float16 w1t[EMB][72];       // transposed W1 fp16, padded
    __shared__ float redS[4][EMB], redQ[4][EMB];

    const int tid  = threadIdx.x;
    const int lane = tid & 63;
    const int wid  = tid >> 6;
    const int l15  = lane & 15;
    const int kb   = lane >> 4;

    #pragma unroll
    for (int i = 0; i < 32; ++i) {
        int idx = i * 256 + tid;            // 0..8191
        int k = idx >> 7, c = idx & 127;
        w1t[c][k] = (_Float16)W1[idx];
    }
    float b1c[8];
    #pragma unroll
    for (int ct = 0; ct < 8; ++ct) b1c[ct] = b1[ct * 16 + l15];
    __syncthreads();

    half8_t Bf[8][2];
    #pragma unroll
    for (int ct = 0; ct < 8; ++ct)
        #pragma unroll
        for (int kc = 0; kc < 2; ++kc)
            Bf[ct][kc] = *(half8_t*)&w1t[ct * 16 + l15][kc * 32 + kb * 8];

    float sA[8] = {0,0,0,0,0,0,0,0};
    float qA[8] = {0,0,0,0,0,0,0,0};

    #pragma unroll
    for (int j = 0; j < GV_TPW; ++j) {
        const int t = blockIdx.x * (4 * GV_TPW) + wid * GV_TPW + j;
        if (t >= GV_TILES) break;
        const size_t rowb = (size_t)(t * 16 + l15) * IN_DIM + kb * 8;
        half8_t af[2];
        #pragma unroll
        for (int kc = 0; kc < 2; ++kc) {
            float4 a0 = *(const float4*)(agg + rowb + kc * 32);
            float4 a1 = *(const float4*)(agg + rowb + kc * 32 + 4);
            float4 x0 = *(const float4*)(x   + rowb + kc * 32);
            float4 x1 = *(const float4*)(x   + rowb + kc * 32 + 4);
            af[kc][0] = (_Float16)(a0.x + x0.x);
            af[kc][1] = (_Float16)(a0.y + x0.y);
            af[kc][2] = (_Float16)(a0.z + x0.z);
            af[kc][3] = (_Float16)(a0.w + x0.w);
            af[kc][4] = (_Float16)(a1.x + x1.x);
            af[kc][5] = (_Float16)(a1.y + x1.y);
            af[kc][6] = (_Float16)(a1.z + x1.z);
            af[kc][7] = (_Float16)(a1.w + x1.w);
        }
        floatx4 acc[8];
        #pragma unroll
        for (int ct = 0; ct < 8; ++ct)
            acc[ct] = (floatx4){b1c[ct], b1c[ct], b1c[ct], b1c[ct]};
        #pragma unroll
        for (int kc = 0; kc < 2; ++kc)
            #pragma unroll
            for (int ct = 0; ct < 8; ++ct)
                acc[ct] = __builtin_amdgcn_mfma_f32_16x16x32_f16(af[kc], Bf[ct][kc], acc[ct], 0, 0, 0);
        #pragma unroll
        for (int ct = 0; ct < 8; ++ct) {
            #pragma unroll
            for (int i = 0; i < 4; ++i) {
                const int r = t * 16 + kb * 4 + i;
                const float v = acc[ct][i];
                h16[(size_t)r * EMB + ct * 16 + l15] = (_Float16)v;
                sA[ct] += v;
                qA[ct] += v * v;
            }
        }
    }

    #pragma unroll
    for (int ct = 0; ct < 8; ++ct) {
        sA[ct] += __shfl_xor(sA[ct], 16); sA[ct] += __shfl_xor(sA[ct], 32);
        qA[ct] += __shfl_xor(qA[ct], 16); qA[ct] += __shfl_xor(qA[ct], 32);
    }
    if (lane < 16) {
        #pragma unroll
        for (int ct = 0; ct < 8; ++ct) {
            redS[wid][ct * 16 + lane] = sA[ct];
            redQ[wid][ct * 16 + lane] = qA[ct];
        }
    }
    __syncthreads();
    if (tid < EMB) {
        float s = redS[0][tid] + redS[1][tid] + redS[2][tid] + redS[3][tid];
        float q = redQ[0][tid] + redQ[1][tid] + redQ[2][tid] + redQ[3][tid];
        pS[(size_t)tid * GV_GRID + blockIdx.x] = s;   // no atomics
        pQ[(size_t)tid * GV_GRID + blockIdx.x] = q;
    }
}

// ---------------- bnred: column-sum partials -> gsum/gsum2 ------------------
__global__ __launch_bounds__(128) void bnred_kernel(
    const float* __restrict__ pS, const float* __restrict__ pQ,
    float* __restrict__ gsum, float* __restrict__ gsum2)
{
    const int c    = blockIdx.x;        // 0..127
    const int lane = threadIdx.x & 63;
    const int w    = threadIdx.x >> 6;  // 0: S, 1: Q
    const float* __restrict__ src = w ? pQ : pS;
    float s = 0.f;
    for (int b = lane; b < GV_GRID; b += 64)
        s += src[(size_t)c * GV_GRID + b];   // coalesced
    #pragma unroll
    for (int off = 32; off > 0; off >>= 1) s += __shfl_xor(s, off);
    if (lane == 0) { if (w) gsum2[c] = s; else gsum[c] = s; }
}

// ---------------- mlp2: out = relu(BN(h16)) @ W2 + b2 (fp16 in, fp32 out) ---
#define MR 32
#define M2_ITERS 5
#define M2_ROWS (MR * M2_ITERS)   // 160 rows/block -> 625 blocks

__global__ __launch_bounds__(256) void mlp2_kernel(
    const _Float16* __restrict__ h16,
    float* __restrict__ out,
    const float* __restrict__ gsum, const float* __restrict__ gsum2,
    const float* __restrict__ gamma, const float* __restrict__ beta,
    const float* __restrict__ W2,   // [128,128] row-major, fp32
    const float* __restrict__ b2)
{
    __shared__ _Float16 Ph[MR][136];
    __shared__ float abuf[EMB], bbuf[EMB];

    const int tid  = threadIdx.x;
    const int lane = tid & 63;
    const int wid  = tid >> 6;
    const int rg   = wid >> 1;
    const int ch   = wid & 1;
    const int c0w  = ch * 64;
    const int l15  = lane & 15;
    const int kb   = lane >> 4;

    if (tid < EMB) {
        const float invN = 1.0f / (float)N_NODES;
        float mean = gsum[tid] * invN;
        float var  = gsum2[tid] * invN - mean * mean;
        float inv  = rsqrtf(var + BN_EPS);
        float a    = gamma[tid] * inv;
        abuf[tid] = a;
        bbuf[tid] = beta[tid] - mean * a;
    }

    const int bcol = c0w + l15;
    half8_t Bf[4][4];
    #pragma unroll
    for (int ct = 0; ct < 4; ++ct) {
        #pragma unroll
        for (int kc = 0; kc < 4; ++kc) {
            #pragma unroll
            for (int i = 0; i < 8; ++i)
                Bf[ct][kc][i] = (_Float16)W2[(kc * 32 + kb * 8 + i) * EMB + ct * 16 + bcol];
        }
    }
    float b2c[4];
    #pragma unroll
    for (int ct = 0; ct < 4; ++ct) b2c[ct] = b2[ct * 16 + bcol];

    __syncthreads();

    const int r0blk = blockIdx.x * M2_ROWS;
    for (int it = 0; it < M2_ITERS; ++it) {
        const int r0 = r0blk + it * MR;
        #pragma unroll
        for (int i = 0; i < 8; ++i) {
            int j   = i * 256 + tid;
            int row = j >> 6;
            int c2  = (j & 63) * 2;
            half2_t hv = *(const half2_t*)&h16[(size_t)(r0 + row) * EMB + c2];
            float p0 = fmaxf((float)hv[0] * abuf[c2]     + bbuf[c2],     0.f);
            float p1 = fmaxf((float)hv[1] * abuf[c2 + 1] + bbuf[c2 + 1], 0.f);
            Ph[row][c2]     = (_Float16)p0;
            Ph[row][c2 + 1] = (_Float16)p1;
        }
        __syncthreads();

        floatx4 acc[4];
        #pragma unroll
        for (int ct = 0; ct < 4; ++ct)
            acc[ct] = (floatx4){b2c[ct], b2c[ct], b2c[ct], b2c[ct]};
        #pragma unroll
        for (int kc = 0; kc < 4; ++kc) {
            half8_t af = *(half8_t*)&Ph[rg * 16 + l15][kc * 32 + kb * 8];
            #pragma unroll
            for (int ct = 0; ct < 4; ++ct)
                acc[ct] = __builtin_amdgcn_mfma_f32_16x16x32_f16(af, Bf[ct][kc], acc[ct], 0, 0, 0);
        }
        __syncthreads();

        #pragma unroll
        for (int ct = 0; ct < 4; ++ct) {
            #pragma unroll
            for (int i = 0; i < 4; ++i) {
                int row = r0 + rg * 16 + kb * 4 + i;
                out[(size_t)row * EMB + c0w + ct * 16 + l15] = acc[ct][i];
            }
        }
    }
}

extern "C" void kernel_launch(void* const* d_in, const int* in_sizes, int n_in,
                              void* d_out, int out_size, void* d_ws, size_t ws_size,
                              hipStream_t stream)
{
    const float* x     = (const float*)d_in[0];
    const int*   ei    = (const int*)d_in[1];   // int32 [2,E]
    const float* ew    = (const float*)d_in[3];
    const float* W1    = (const float*)d_in[4];
    const float* b1    = (const float*)d_in[5];
    const float* gamma = (const float*)d_in[6];
    const float* beta  = (const float*)d_in[7];
    const float* W2    = (const float*)d_in[8];
    const float* b2    = (const float*)d_in[9];

    char* ws = (char*)d_ws;
    float*    gsum     = (float*)(ws + WS_GSUM);
    float*    gsum2    = (float*)(ws + WS_GSUM2);
    int*      bcur     = (int*)(ws + WS_BCUR);
    int*      rowstart = (int*)(ws + WS_ROWSTART);
    float2*   pairs    = (float2*)(ws + WS_PAIRS);
    float*    agg      = (float*)(ws + WS_AGG);
    _Float16* h16      = (_Float16*)(ws + WS_AGG);   // overlays agg (tile-local RAW safe)
    int*      dstArr   = (int*)(ws + WS_DSTARR);
    float2*   swArr    = (float2*)(ws + WS_SWARR);
    _Float16* x16      = (_Float16*)(ws + WS_X16);
    float*    pS       = (float*)(ws + WS_PART);
    float*    pQ       = (float*)(ws + WS_PART + 128 * GV_GRID * 4);
    float*    out      = (float*)d_out;

    zero_kernel<<<1, WS_ZERO_INTS, 0, stream>>>((int*)d_ws);
    fillA_kernel<<<FA_GRID, FA_THREADS, 0, stream>>>(ei, ew, bcur, dstArr, swArr);
    fillB2_kernel<<<NB, 1024, 0, stream>>>(bcur, dstArr, swArr, rowstart, pairs);
    cvt_kernel<<<(N_NODES * IN_DIM / 4 + 255) / 256, 256, 0, stream>>>(
        (const float4*)x, (ushort4*)x16);
    gather_kernel<<<N_NODES / (4 * G_NPW), 256, 0, stream>>>(x16, rowstart, pairs, agg);
    gemv_kernel<<<GV_GRID, 256, 0, stream>>>(agg, x, W1, b1, h16, pS, pQ);
    bnred_kernel<<<EMB, 128, 0, stream>>>(pS, pQ, gsum, gsum2);
    mlp2_kernel<<<N_NODES / M2_ROWS, 256, 0, stream>>>(h16, out, gsum, gsum2, gamma, beta, W2, b2);
}

// Round 29
// 139.167 us; speedup vs baseline: 1.5002x; 1.0874x over previous
//
#include <hip/hip_runtime.h>

#define N_NODES 100000
#define IN_DIM 64
#define EMB 128
#define N_EDGES 1600000
#define BN_EPS 1e-5f

// bucket partition
#define NB 98
#define BCAP 18432
#define FA_THREADS 512
#define FA_BLK 8192
#define FA_GRID ((N_EDGES + FA_BLK - 1) / FA_BLK)   // 196

// gemv tiling (r24 v4 + r28 atomic-free BN)
#define GV_TPW 3
#define GV_TILES (N_NODES / 16)                       // 6250
#define GV_GRID ((GV_TILES + 4 * GV_TPW - 1) / (4 * GV_TPW))   // 521

// ---- workspace layout (bytes) ----
#define WS_GSUM     0
#define WS_GSUM2    512
#define WS_BCUR     1024
#define WS_ROWSTART 2048                    // ends 402052
#define WS_PAIRS    802304                  // 12.8 MB
#define WS_AGG      13602304                // 25.6 MB (h16 overlays after gemv reads)
#define WS_SWARR    39202304                // 98*18432*8 = 14,450,688 -> ends 53,652,992
#define WS_X16      WS_SWARR                // 12.8 MB overlay (swArr dead after fillB2)
#define WS_PART     53653248                // 2*128*521*4 = 533,504
#define WS_ZERO_INTS 512

typedef _Float16 half8_t __attribute__((ext_vector_type(8)));
typedef _Float16 half4_t __attribute__((ext_vector_type(4)));
typedef _Float16 half2_t __attribute__((ext_vector_type(2)));
typedef float floatx4 __attribute__((ext_vector_type(4)));

// ---------------- zero: replaces hipMemsetAsync -----------------------------
__global__ __launch_bounds__(512) void zero_kernel(int* __restrict__ p)
{
    p[threadIdx.x] = 0;
}

// ---------------- fillA v3: packed 8B records, single scattered stream ------
// rec.x = src | dstlocal<<17 (src<2^17, dstlocal<2^10); rec.y = bits(w).
// pk packs (b<<23 | dstlocal<<13 | pos) so phase 2 never re-reads dst.
__global__ __launch_bounds__(512) void fillA_kernel(
    const int* __restrict__ ei, const float* __restrict__ ew,
    int* __restrict__ bcur, uint2* __restrict__ swArr)
{
    __shared__ int cnt[NB], base[NB];
    const int tid = threadIdx.x;
    if (tid < NB) cnt[tid] = 0;
    __syncthreads();
    const int e0 = blockIdx.x * FA_BLK;
    int pk[16];
    #pragma unroll
    for (int i = 0; i < 4; ++i) {
        int e = e0 + (i * 512 + tid) * 4;
        if (e < N_EDGES) {
            int4 d4 = *(const int4*)(ei + N_EDGES + e);
            int dv[4] = {d4.x, d4.y, d4.z, d4.w};
            #pragma unroll
            for (int k = 0; k < 4; ++k) {
                int d = dv[k];
                int b = d >> 10;
                int pos = atomicAdd(&cnt[b], 1);   // LDS atomic; pos < 8192
                pk[i * 4 + k] = (b << 23) | ((d & 1023) << 13) | pos;
            }
        } else {
            #pragma unroll
            for (int k = 0; k < 4; ++k) pk[i * 4 + k] = -1;
        }
    }
    __syncthreads();
    if (tid < NB) base[tid] = atomicAdd(&bcur[tid], cnt[tid]);
    __syncthreads();
    #pragma unroll
    for (int i = 0; i < 4; ++i) {
        int e = e0 + (i * 512 + tid) * 4;
        if (e < N_EDGES) {
            int4   s4 = *(const int4*)(ei + e);
            float4 w4 = *(const float4*)(ew + e);
            int   sv[4] = {s4.x, s4.y, s4.z, s4.w};
            float wv[4] = {w4.x, w4.y, w4.z, w4.w};
            #pragma unroll
            for (int k = 0; k < 4; ++k) {
                int p   = pk[i * 4 + k];
                int b   = p >> 23;
                int dl  = (p >> 13) & 1023;
                int pos = p & 8191;
                int idx = b * BCAP + base[b] + pos;
                swArr[idx] = make_uint2((unsigned)sv[k] | ((unsigned)dl << 17),
                                        __float_as_uint(wv[k]));
            }
        }
    }
}

// ---------------- fillB2 v2: hist + scan + rowstart + scatter (packed) ------
__global__ __launch_bounds__(1024) void fillB2_kernel(
    const int* __restrict__ bcur, const uint2* __restrict__ swArr,
    int* __restrict__ rowstart, float2* __restrict__ pairs)
{
    __shared__ int cnt2[1024];
    __shared__ int pre[1024];
    __shared__ int sbk[128];
    const int g = blockIdx.x;
    const int tid = threadIdx.x;

    if (tid < 128) sbk[tid] = (tid < NB) ? bcur[tid] : 0;
    cnt2[tid] = 0;
    __syncthreads();
    for (int off = 1; off < 128; off <<= 1) {
        int v = 0;
        if (tid < 128 && tid >= off) v = sbk[tid - off];
        __syncthreads();
        if (tid < 128) sbk[tid] += v;
        __syncthreads();
    }
    const int bucketBase = (g > 0) ? sbk[g - 1] : 0;

    const int nE = bcur[g];
    const size_t segBase = (size_t)g * BCAP;
    for (int j = tid; j < nE; j += 1024)
        atomicAdd(&cnt2[swArr[segBase + j].x >> 17], 1);   // LDS atomic
    __syncthreads();

    const int c = cnt2[tid];
    pre[tid] = c;
    __syncthreads();
    for (int off = 1; off < 1024; off <<= 1) {
        int v = (tid >= off) ? pre[tid - off] : 0;
        __syncthreads();
        pre[tid] += v;
        __syncthreads();
    }
    const int start = bucketBase + pre[tid] - c;
    const int node = g * 1024 + tid;
    if (node < N_NODES) rowstart[node] = start;
    if (node == N_NODES - 1) rowstart[N_NODES] = start + c;

    __syncthreads();
    cnt2[tid] = start;
    __syncthreads();
    #pragma unroll 4
    for (int j = tid; j < nE; j += 1024) {
        uint2 rec = swArr[segBase + j];
        int p = atomicAdd(&cnt2[rec.x >> 17], 1);   // LDS atomic, block-owned
        pairs[p] = make_float2(__int_as_float((int)(rec.x & 0x1FFFFu)),
                               __uint_as_float(rec.y));
    }
}

// ---------------- cvt: x -> fp16 sidecar ------------------------------------
__global__ __launch_bounds__(256) void cvt_kernel(
    const float4* __restrict__ x4, ushort4* __restrict__ x16)
{
    int i = blockIdx.x * 256 + threadIdx.x;
    if (i >= N_NODES * IN_DIM / 4) return;
    float4 v = x4[i];
    ushort4 u;
    _Float16 a = (_Float16)v.x, b = (_Float16)v.y,
             c = (_Float16)v.z, d = (_Float16)v.w;
    u.x = *(unsigned short*)&a; u.y = *(unsigned short*)&b;
    u.z = *(unsigned short*)&c; u.w = *(unsigned short*)&d;
    x16[i] = u;
}

// ---------------- gather v4: e/f lane map on fp16 rows ----------------------
#define G_NPW 5
__global__ __launch_bounds__(256) void gather_kernel(
    const _Float16* __restrict__ x16,
    const int* __restrict__ rowstart,
    const float2* __restrict__ pairs,
    float* __restrict__ agg)
{
    const int tid  = threadIdx.x;
    const int lane = tid & 63;
    const int wid  = tid >> 6;
    const int e    = lane >> 4;
    const int f    = lane & 15;
    const half4_t* __restrict__ xv4 = (const half4_t*)x16;
    const int node0 = (blockIdx.x * 4 + wid) * G_NPW;

    for (int r = 0; r < G_NPW; ++r) {
        const int n  = node0 + r;
        const int jb = rowstart[n];
        const int je = rowstart[n + 1];
        float4 accA = make_float4(0.f, 0.f, 0.f, 0.f);
        float4 accB = make_float4(0.f, 0.f, 0.f, 0.f);
        for (int j0 = jb; j0 < je; j0 += 64) {
            const int cnt = min(64, je - j0);
            float2 p = (lane < cnt) ? pairs[j0 + lane] : make_float2(0.f, 0.f);
            int   psrc = __float_as_int(p.x);
            float pw   = p.y;
            const int nch = (cnt + 7) >> 3;
            #pragma unroll 4
            for (int c = 0; c < nch; ++c) {
                int   uA = __shfl(psrc, c * 8 + e);
                float wA = __shfl(pw,   c * 8 + e);
                int   uB = __shfl(psrc, c * 8 + 4 + e);
                float wB = __shfl(pw,   c * 8 + 4 + e);
                half4_t va = xv4[(size_t)(unsigned)uA * 16 + f];
                half4_t vb = xv4[(size_t)(unsigned)uB * 16 + f];
                accA.x += wA * (float)va[0]; accA.y += wA * (float)va[1];
                accA.z += wA * (float)va[2]; accA.w += wA * (float)va[3];
                accB.x += wB * (float)vb[0]; accB.y += wB * (float)vb[1];
                accB.z += wB * (float)vb[2]; accB.w += wB * (float)vb[3];
            }
        }
        float4 s = make_float4(accA.x + accB.x, accA.y + accB.y,
                               accA.z + accB.z, accA.w + accB.w);
        s.x += __shfl_xor(s.x, 16); s.y += __shfl_xor(s.y, 16);
        s.z += __shfl_xor(s.z, 16); s.w += __shfl_xor(s.w, 16);
        s.x += __shfl_xor(s.x, 32); s.y += __shfl_xor(s.y, 32);
        s.z += __shfl_xor(s.z, 32); s.w += __shfl_xor(s.w, 32);
        if (e == 0)
            *(float4*)&agg[(size_t)n * IN_DIM + f * 4] = s;
    }
}

// ---------------- gemv v4b: LDS W1 + direct A + fp16 h out + partials -------
__global__ __launch_bounds__(256) void gemv_kernel(
    const float* __restrict__ agg,
    const float* __restrict__ x,
    const float* __restrict__ W1,   // [64,128] row-major, fp32
    const float* __restrict__ b1,
    _Float16* __restrict__ h16,     // [N,128] fp16 (overlays agg)
    float* __restrict__ pS, float* __restrict__ pQ)   // [128][GV_GRID]
{
    __shared__ _Float16 w1t[EMB][72];
    __shared__ float redS[4][EMB], redQ[4][EMB];

    const int tid  = threadIdx.x;
    const int lane = tid & 63;
    const int wid  = tid >> 6;
    const int l15  = lane & 15;
    const int kb   = lane >> 4;

    #pragma unroll
    for (int i = 0; i < 32; ++i) {
        int idx = i * 256 + tid;
        int k = idx >> 7, c = idx & 127;
        w1t[c][k] = (_Float16)W1[idx];
    }
    float b1c[8];
    #pragma unroll
    for (int ct = 0; ct < 8; ++ct) b1c[ct] = b1[ct * 16 + l15];
    __syncthreads();

    half8_t Bf[8][2];
    #pragma unroll
    for (int ct = 0; ct < 8; ++ct)
        #pragma unroll
        for (int kc = 0; kc < 2; ++kc)
            Bf[ct][kc] = *(half8_t*)&w1t[ct * 16 + l15][kc * 32 + kb * 8];

    float sA[8] = {0,0,0,0,0,0,0,0};
    float qA[8] = {0,0,0,0,0,0,0,0};

    #pragma unroll
    for (int j = 0; j < GV_TPW; ++j) {
        const int t = blockIdx.x * (4 * GV_TPW) + wid * GV_TPW + j;
        if (t >= GV_TILES) break;
        const size_t rowb = (size_t)(t * 16 + l15) * IN_DIM + kb * 8;
        half8_t af[2];
        #pragma unroll
        for (int kc = 0; kc < 2; ++kc) {
            float4 a0 = *(const float4*)(agg + rowb + kc * 32);
            float4 a1 = *(const float4*)(agg + rowb + kc * 32 + 4);
            float4 x0 = *(const float4*)(x   + rowb + kc * 32);
            float4 x1 = *(const float4*)(x   + rowb + kc * 32 + 4);
            af[kc][0] = (_Float16)(a0.x + x0.x);
            af[kc][1] = (_Float16)(a0.y + x0.y);
            af[kc][2] = (_Float16)(a0.z + x0.z);
            af[kc][3] = (_Float16)(a0.w + x0.w);
            af[kc][4] = (_Float16)(a1.x + x1.x);
            af[kc][5] = (_Float16)(a1.y + x1.y);
            af[kc][6] = (_Float16)(a1.z + x1.z);
            af[kc][7] = (_Float16)(a1.w + x1.w);
        }
        floatx4 acc[8];
        #pragma unroll
        for (int ct = 0; ct < 8; ++ct)
            acc[ct] = (floatx4){b1c[ct], b1c[ct], b1c[ct], b1c[ct]};
        #pragma unroll
        for (int kc = 0; kc < 2; ++kc)
            #pragma unroll
            for (int ct = 0; ct < 8; ++ct)
                acc[ct] = __builtin_amdgcn_mfma_f32_16x16x32_f16(af[kc], Bf[ct][kc], acc[ct], 0, 0, 0);
        #pragma unroll
        for (int ct = 0; ct < 8; ++ct) {
            #pragma unroll
            for (int i = 0; i < 4; ++i) {
                const int r = t * 16 + kb * 4 + i;
                const float v = acc[ct][i];
                h16[(size_t)r * EMB + ct * 16 + l15] = (_Float16)v;
                sA[ct] += v;
                qA[ct] += v * v;
            }
        }
    }

    #pragma unroll
    for (int ct = 0; ct < 8; ++ct) {
        sA[ct] += __shfl_xor(sA[ct], 16); sA[ct] += __shfl_xor(sA[ct], 32);
        qA[ct] += __shfl_xor(qA[ct], 16); qA[ct] += __shfl_xor(qA[ct], 32);
    }
    if (lane < 16) {
        #pragma unroll
        for (int ct = 0; ct < 8; ++ct) {
            redS[wid][ct * 16 + lane] = sA[ct];
            redQ[wid][ct * 16 + lane] = qA[ct];
        }
    }
    __syncthreads();
    if (tid < EMB) {
        float s = redS[0][tid] + redS[1][tid] + redS[2][tid] + redS[3][tid];
        float q = redQ[0][tid] + redQ[1][tid] + redQ[2][tid] + redQ[3][tid];
        pS[(size_t)tid * GV_GRID + blockIdx.x] = s;   // no atomics
        pQ[(size_t)tid * GV_GRID + blockIdx.x] = q;
    }
}

// ---------------- bnred: column-sum partials -> gsum/gsum2 ------------------
__global__ __launch_bounds__(128) void bnred_kernel(
    const float* __restrict__ pS, const float* __restrict__ pQ,
    float* __restrict__ gsum, float* __restrict__ gsum2)
{
    const int c    = blockIdx.x;
    const int lane = threadIdx.x & 63;
    const int w    = threadIdx.x >> 6;
    const float* __restrict__ src = w ? pQ : pS;
    float s = 0.f;
    for (int b = lane; b < GV_GRID; b += 64)
        s += src[(size_t)c * GV_GRID + b];
    #pragma unroll
    for (int off = 32; off > 0; off >>= 1) s += __shfl_xor(s, off);
    if (lane == 0) { if (w) gsum2[c] = s; else gsum[c] = s; }
}

// ---------------- mlp2: out = relu(BN(h16)) @ W2 + b2 (fp16 in, fp32 out) ---
#define MR 32
#define M2_ITERS 5
#define M2_ROWS (MR * M2_ITERS)   // 160 rows/block -> 625 blocks

__global__ __launch_bounds__(256) void mlp2_kernel(
    const _Float16* __restrict__ h16,
    float* __restrict__ out,
    const float* __restrict__ gsum, const float* __restrict__ gsum2,
    const float* __restrict__ gamma, const float* __restrict__ beta,
    const float* __restrict__ W2,   // [128,128] row-major, fp32
    const float* __restrict__ b2)
{
    __shared__ _Float16 Ph[MR][136];
    __shared__ float abuf[EMB], bbuf[EMB];

    const int tid  = threadIdx.x;
    const int lane = tid & 63;
    const int wid  = tid >> 6;
    const int rg   = wid >> 1;
    const int ch   = wid & 1;
    const int c0w  = ch * 64;
    const int l15  = lane & 15;
    const int kb   = lane >> 4;

    if (tid < EMB) {
        const float invN = 1.0f / (float)N_NODES;
        float mean = gsum[tid] * invN;
        float var  = gsum2[tid] * invN - mean * mean;
        float inv  = rsqrtf(var + BN_EPS);
        float a    = gamma[tid] * inv;
        abuf[tid] = a;
        bbuf[tid] = beta[tid] - mean * a;
    }

    const int bcol = c0w + l15;
    half8_t Bf[4][4];
    #pragma unroll
    for (int ct = 0; ct < 4; ++ct) {
        #pragma unroll
        for (int kc = 0; kc < 4; ++kc) {
            #pragma unroll
            for (int i = 0; i < 8; ++i)
                Bf[ct][kc][i] = (_Float16)W2[(kc * 32 + kb * 8 + i) * EMB + ct * 16 + bcol];
        }
    }
    float b2c[4];
    #pragma unroll
    for (int ct = 0; ct < 4; ++ct) b2c[ct] = b2[ct * 16 + bcol];

    __syncthreads();

    const int r0blk = blockIdx.x * M2_ROWS;
    for (int it = 0; it < M2_ITERS; ++it) {
        const int r0 = r0blk + it * MR;
        #pragma unroll
        for (int i = 0; i < 8; ++i) {
            int j   = i * 256 + tid;
            int row = j >> 6;
            int c2  = (j & 63) * 2;
            half2_t hv = *(const half2_t*)&h16[(size_t)(r0 + row) * EMB + c2];
            float p0 = fmaxf((float)hv[0] * abuf[c2]     + bbuf[c2],     0.f);
            float p1 = fmaxf((float)hv[1] * abuf[c2 + 1] + bbuf[c2 + 1], 0.f);
            Ph[row][c2]     = (_Float16)p0;
            Ph[row][c2 + 1] = (_Float16)p1;
        }
        __syncthreads();

        floatx4 acc[4];
        #pragma unroll
        for (int ct = 0; ct < 4; ++ct)
            acc[ct] = (floatx4){b2c[ct], b2c[ct], b2c[ct], b2c[ct]};
        #pragma unroll
        for (int kc = 0; kc < 4; ++kc) {
            half8_t af = *(half8_t*)&Ph[rg * 16 + l15][kc * 32 + kb * 8];
            #pragma unroll
            for (int ct = 0; ct < 4; ++ct)
                acc[ct] = __builtin_amdgcn_mfma_f32_16x16x32_f16(af, Bf[ct][kc], acc[ct], 0, 0, 0);
        }
        __syncthreads();

        #pragma unroll
        for (int ct = 0; ct < 4; ++ct) {
            #pragma unroll
            for (int i = 0; i < 4; ++i) {
                int row = r0 + rg * 16 + kb * 4 + i;
                out[(size_t)row * EMB + c0w + ct * 16 + l15] = acc[ct][i];
            }
        }
    }
}

extern "C" void kernel_launch(void* const* d_in, const int* in_sizes, int n_in,
                              void* d_out, int out_size, void* d_ws, size_t ws_size,
                              hipStream_t stream)
{
    const float* x     = (const float*)d_in[0];
    const int*   ei    = (const int*)d_in[1];   // int32 [2,E]
    const float* ew    = (const float*)d_in[3];
    const float* W1    = (const float*)d_in[4];
    const float* b1    = (const float*)d_in[5];
    const float* gamma = (const float*)d_in[6];
    const float* beta  = (const float*)d_in[7];
    const float* W2    = (const float*)d_in[8];
    const float* b2    = (const float*)d_in[9];

    char* ws = (char*)d_ws;
    float*    gsum     = (float*)(ws + WS_GSUM);
    float*    gsum2    = (float*)(ws + WS_GSUM2);
    int*      bcur     = (int*)(ws + WS_BCUR);
    int*      rowstart = (int*)(ws + WS_ROWSTART);
    float2*   pairs    = (float2*)(ws + WS_PAIRS);
    float*    agg      = (float*)(ws + WS_AGG);
    _Float16* h16      = (_Float16*)(ws + WS_AGG);   // overlays agg (tile-local RAW safe)
    uint2*    swArr    = (uint2*)(ws + WS_SWARR);
    _Float16* x16      = (_Float16*)(ws + WS_X16);   // overlays swArr (dead after fillB2)
    float*    pS       = (float*)(ws + WS_PART);
    float*    pQ       = (float*)(ws + WS_PART + 128 * GV_GRID * 4);
    float*    out      = (float*)d_out;

    zero_kernel<<<1, WS_ZERO_INTS, 0, stream>>>((int*)d_ws);
    fillA_kernel<<<FA_GRID, FA_THREADS, 0, stream>>>(ei, ew, bcur, swArr);
    fillB2_kernel<<<NB, 1024, 0, stream>>>(bcur, swArr, rowstart, pairs);
    cvt_kernel<<<(N_NODES * IN_DIM / 4 + 255) / 256, 256, 0, stream>>>(
        (const float4*)x, (ushort4*)x16);
    gather_kernel<<<N_NODES / (4 * G_NPW), 256, 0, stream>>>(x16, rowstart, pairs, agg);
    gemv_kernel<<<GV_GRID, 256, 0, stream>>>(agg, x, W1, b1, h16, pS, pQ);
    bnred_kernel<<<EMB, 128, 0, stream>>>(pS, pQ, gsum, gsum2);
    mlp2_kernel<<<N_NODES / M2_ROWS, 256, 0, stream>>>(h16, out, gsum, gsum2, gamma, beta, W2, b2);
}